// Round 6
// baseline (197.771 us; speedup 1.0000x reference)
//
#include <hip/hip_runtime.h>

// GCN, algebraically collapsed + two-sided 256-node bucket partition.
//   y[n]  = dinv[n]*x[n]
//   a[d]  = dinv[d]*(sum_{s->d} y[s] + y[d])
//   h1[d] = relu(a[d] @ W1 + b1)
//   c[d]  = dinv[d]*sdeg[d] + dinv[d]^2,  sdeg[s] = sum_{d: s->d} dinv[d]
//   v     = sum_d c[d]*h1[d];  g = (1/N)*v@W2 + b2
//   out   = concat(g, relu(state@Wm+bm)) @ Wc + bc
// R6: batch-4 independent gathers per thread (MLP was ~1-2 loads/wave:
// R5 showed occupancy 14->33% changed nothing -> latency-bound, not
// occupancy-bound) + nontemporal loads on the use-once edge streams so y/dinv
// stay L2-resident.

#define NPB   256      // nodes per bucket (power of 2)
#define CAP   4096     // edge capacity per bucket (Poisson mean ~3197, +15.9 sigma)
#define MAXB  512      // max buckets (N <= 131072)
#define PCH   4096     // edges per partition block
#define PTH   512      // partition block threads
#define PK    (PCH/PTH) // 8 edges per thread

typedef unsigned uv4 __attribute__((ext_vector_type(4)));

// Block-level radix scatter: per 4096-edge chunk, rank edges into buckets via
// LDS atomics, exclusive-scan counts, stage bucket-ordered in LDS, then write
// contiguous runs to global (consecutive lanes -> consecutive addresses).
// Payload u32: low 17 bits = other-endpoint node id, bits [24:17] = own low-8.
__launch_bounds__(PTH)
__global__ void k_part(const int* __restrict__ src, const int* __restrict__ dst,
                       int E, int nbuck,
                       unsigned* __restrict__ curD, unsigned* __restrict__ curS,
                       unsigned* __restrict__ bufD, unsigned* __restrict__ bufS) {
    __shared__ unsigned       stage[PCH];   // 16 KB
    __shared__ unsigned short bkt[PCH];     //  8 KB
    __shared__ unsigned lc[MAXB], lofs[MAXB], gb[MAXB], sc[MAXB]; // 8 KB
    int t = threadIdx.x;
    int base = blockIdx.x * PCH;
    int cnt = min(PCH, E - base);

    unsigned ss[PK], dd[PK];
#pragma unroll
    for (int k = 0; k < PK; ++k) {
        int e = base + k * PTH + t;
        if (e < E) {
            ss[k] = (unsigned)__builtin_nontemporal_load(src + e);
            dd[k] = (unsigned)__builtin_nontemporal_load(dst + e);
        } else ss[k] = 0xffffffffu;
    }

    for (int side = 0; side < 2; ++side) {
        lc[t] = 0;             // PTH == MAXB
        __syncthreads();

        unsigned br[PK];
#pragma unroll
        for (int k = 0; k < PK; ++k) {
            if (ss[k] == 0xffffffffu) { br[k] = 0xffffffffu; continue; }
            unsigned key = side ? ss[k] : dd[k];
            unsigned b = key >> 8;
            unsigned r = atomicAdd(&lc[b], 1u);
            br[k] = (b << 16) | r;
        }
        __syncthreads();

        // exclusive scan of lc[0..MAXB) with PTH==MAXB threads
        unsigned v = lc[t];
        sc[t] = v;
        __syncthreads();
        for (int o = 1; o < MAXB; o <<= 1) {
            unsigned add = (t >= o) ? sc[t - o] : 0u;
            __syncthreads();
            sc[t] += add;
            __syncthreads();
        }
        lofs[t] = sc[t] - v;
        gb[t] = v ? atomicAdd(side ? &curS[t] : &curD[t], v) : 0u;
        __syncthreads();

        // stage bucket-ordered
#pragma unroll
        for (int k = 0; k < PK; ++k) {
            if (br[k] == 0xffffffffu) continue;
            unsigned b = br[k] >> 16, r = br[k] & 0xffffu;
            unsigned pos = lofs[b] + r;
            stage[pos] = side ? (dd[k] | ((ss[k] & 255u) << 17))
                              : (ss[k] | ((dd[k] & 255u) << 17));
            bkt[pos] = (unsigned short)b;
        }
        __syncthreads();

        // contiguous-run writeout (nontemporal: consumed once, next kernel)
        unsigned* obuf = side ? bufS : bufD;
        for (int i = t; i < cnt; i += PTH) {
            unsigned b = bkt[i];
            __builtin_nontemporal_store(stage[i],
                &obuf[(size_t)b * CAP + gb[b] + ((unsigned)i - lofs[b])]);
        }
        __syncthreads();
    }
}

// Per dst-bucket: in-degree via LDS atomics -> dinv, y = dinv*x (coalesced).
// Batch-4 edge words per thread (CAP == 4*1024).
__launch_bounds__(1024)
__global__ void k_prep(const unsigned* __restrict__ bufD, const unsigned* __restrict__ cntD,
                       const float* __restrict__ x, int N,
                       float* __restrict__ dinv, float* __restrict__ y) {
    __shared__ unsigned degl[NPB];
    int t = threadIdx.x, b = blockIdx.x;
    if (t < NPB) degl[t] = 0u;
    __syncthreads();
    unsigned cnt = cntD[b];
    unsigned base = (unsigned)t * 4u;
    if (base < cnt) {
        uv4 w = __builtin_nontemporal_load((const uv4*)(bufD + (size_t)b * CAP) + t);
        unsigned nv = min(cnt - base, 4u);
#pragma unroll
        for (unsigned k = 0; k < 4; ++k)
            if (k < nv) atomicAdd(&degl[w[k] >> 17], 1u);
    }
    __syncthreads();
    if (t < NPB) {
        int n = b * NPB + t;
        if (n < N) {
            float di = rsqrtf((float)(degl[t] + 1u));
            dinv[n] = di;
            float4 u0 = ((const float4*)(x + (size_t)n * 8))[0];
            float4 u1 = ((const float4*)(x + (size_t)n * 8))[1];
            u0.x *= di; u0.y *= di; u0.z *= di; u0.w *= di;
            u1.x *= di; u1.y *= di; u1.z *= di; u1.w *= di;
            ((float4*)(y + (size_t)n * 8))[0] = u0;
            ((float4*)(y + (size_t)n * 8))[1] = u1;
        }
    }
}

// Per bucket b: sl[t] = sdeg (LDS atomics over bufS); acc[t] = sum of in-edge
// y[src] (LDS atomics over bufD); then fused node math + butterfly
// reduce-scatter; block result folds into global vsum[64].
// Batch-4: thread t owns edge slots 4t..4t+3 -> 4 independent gathers in
// flight before first use.
__launch_bounds__(1024, 4)
__global__ void k_sacc(const unsigned* __restrict__ bufD, const unsigned* __restrict__ cntD,
                       const unsigned* __restrict__ bufS, const unsigned* __restrict__ cntS,
                       const float* __restrict__ y, const float* __restrict__ dinv,
                       const float* __restrict__ W1, const float* __restrict__ b1,
                       float* __restrict__ vsum, int N) {
    __shared__ float acc[NPB][9];   // +1 pad: spread dl*9 across all 32 banks
    __shared__ float sl[NPB];
    __shared__ float W1s[512];
    __shared__ float b1s[64];
    __shared__ float red[4][64];
    int t = threadIdx.x, b = blockIdx.x;
    if (t < 512) W1s[t] = W1[t];
    else if (t < 576) b1s[t - 512] = b1[t - 512];
    if (t < NPB) {
#pragma unroll
        for (int j = 0; j < 9; ++j) acc[t][j] = 0.f;
        sl[t] = 0.f;
    }
    __syncthreads();

    unsigned base = (unsigned)t * 4u;

    // sdeg side (src-bucket b): 4 independent dinv gathers
    {
        unsigned cnt = cntS[b];
        if (base < cnt) {
            uv4 w = __builtin_nontemporal_load((const uv4*)(bufS + (size_t)b * CAP) + t);
            unsigned nv = min(cnt - base, 4u);
            float dv[4];
#pragma unroll
            for (unsigned k = 0; k < 4; ++k)
                dv[k] = (k < nv) ? dinv[w[k] & 0x1ffffu] : 0.f;
#pragma unroll
            for (unsigned k = 0; k < 4; ++k)
                if (k < nv) atomicAdd(&sl[w[k] >> 17], dv[k]);
        }
    }
    // feature side (dst-bucket b): 4 independent 32B y gathers
    {
        unsigned cnt = cntD[b];
        if (base < cnt) {
            uv4 w = __builtin_nontemporal_load((const uv4*)(bufD + (size_t)b * CAP) + t);
            unsigned nv = min(cnt - base, 4u);
            float4 g0[4], g1[4];
#pragma unroll
            for (unsigned k = 0; k < 4; ++k) {
                if (k < nv) {
                    unsigned s = w[k] & 0x1ffffu;
                    g0[k] = ((const float4*)(y + (size_t)s * 8))[0];
                    g1[k] = ((const float4*)(y + (size_t)s * 8))[1];
                }
            }
#pragma unroll
            for (unsigned k = 0; k < 4; ++k) {
                if (k >= nv) continue;
                unsigned dl = w[k] >> 17;
                atomicAdd(&acc[dl][0], g0[k].x);
                atomicAdd(&acc[dl][1], g0[k].y);
                atomicAdd(&acc[dl][2], g0[k].z);
                atomicAdd(&acc[dl][3], g0[k].w);
                atomicAdd(&acc[dl][4], g1[k].x);
                atomicAdd(&acc[dl][5], g1[k].y);
                atomicAdd(&acc[dl][6], g1[k].z);
                atomicAdd(&acc[dl][7], g1[k].w);
            }
        }
    }
    __syncthreads();

    if (t < NPB) {
        int n = b * NPB + t;
        float a[8] = {0.f, 0.f, 0.f, 0.f, 0.f, 0.f, 0.f, 0.f};
        float c = 0.f;
        if (n < N) {
            float di = dinv[n];
            float4 s0 = ((const float4*)(y + (size_t)n * 8))[0];
            float4 s1 = ((const float4*)(y + (size_t)n * 8))[1];
            a[0] = di * (acc[t][0] + s0.x);
            a[1] = di * (acc[t][1] + s0.y);
            a[2] = di * (acc[t][2] + s0.z);
            a[3] = di * (acc[t][3] + s0.w);
            a[4] = di * (acc[t][4] + s1.x);
            a[5] = di * (acc[t][5] + s1.y);
            a[6] = di * (acc[t][6] + s1.z);
            a[7] = di * (acc[t][7] + s1.w);
            c = fmaf(di, sl[t], di * di);
        }

        float vv[64];
#pragma unroll
        for (int k = 0; k < 64; ++k) {
            float h = b1s[k];
#pragma unroll
            for (int j = 0; j < 8; ++j) h = fmaf(a[j], W1s[j * 64 + k], h);
            vv[k] = c * fmaxf(h, 0.f);
        }

        // Butterfly reduce-scatter (validated R2-R5): lane l ends with
        // wave-sum of component l in vv[0].
        int lane = t & 63;
#pragma unroll
        for (int half = 32; half >= 1; half >>= 1) {
            bool upper = (lane & half) != 0;
#pragma unroll
            for (int i = 0; i < 32; ++i) {
                if (i >= half) break;
                float lo = vv[i];
                float hi = vv[i + half];
                float give = upper ? lo : hi;
                float keep = upper ? hi : lo;
                float recv = __shfl_xor(give, half);
                vv[i] = keep + recv;
            }
        }
        red[t >> 6][lane] = vv[0];
    }
    __syncthreads();
    if (t < 64)
        unsafeAtomicAdd(&vsum[t], red[0][t] + red[1][t] + red[2][t] + red[3][t]);
}

// Single block, 64 threads: g = (1/N)*vsum@W2+b2, s = relu(state@Wm+bm),
// out = [g,s]@Wc+bc.
__global__ void k_final(const float* __restrict__ vsum,
                        const float* __restrict__ W2, const float* __restrict__ b2,
                        const float* __restrict__ state, const float* __restrict__ Wm,
                        const float* __restrict__ bm, const float* __restrict__ Wc,
                        const float* __restrict__ bc, float* __restrict__ out,
                        float inv_n) {
    __shared__ float v[64];
    __shared__ float gs[128];
    int k = threadIdx.x;   // blockDim = 64

    v[k] = vsum[k];
    __syncthreads();

    float g = 0.f;
    for (int j = 0; j < 64; ++j) g = fmaf(v[j], W2[j * 64 + k], g);
    g = fmaf(g, inv_n, b2[k]);

    float s = bm[k];
    for (int j = 0; j < 8; ++j) s = fmaf(state[j], Wm[j * 64 + k], s);
    s = fmaxf(s, 0.f);

    gs[k] = g;
    gs[64 + k] = s;
    __syncthreads();

    if (k < 2) {
        float o = bc[k];
        for (int j = 0; j < 128; ++j) o = fmaf(gs[j], Wc[j * 2 + k], o);
        out[k] = o;
    }
}

extern "C" void kernel_launch(void* const* d_in, const int* in_sizes, int n_in,
                              void* d_out, int out_size, void* d_ws, size_t ws_size,
                              hipStream_t stream) {
    const float* x     = (const float*)d_in[0];
    const float* state = (const float*)d_in[1];
    const float* W1    = (const float*)d_in[2];
    const float* b1    = (const float*)d_in[3];
    const float* W2    = (const float*)d_in[4];
    const float* b2    = (const float*)d_in[5];
    const float* Wm    = (const float*)d_in[6];
    const float* bm    = (const float*)d_in[7];
    const float* Wc    = (const float*)d_in[8];
    const float* bc    = (const float*)d_in[9];
    const int*   ei    = (const int*)d_in[10];

    const int N = in_sizes[0] / 8;
    const int E = in_sizes[10] / 2;
    const int* src = ei;
    const int* dst = ei + E;
    const int nbuck = (N + NPB - 1) / NPB;   // 391 for N=100000

    char* ws = (char*)d_ws;
    size_t off = 0;
    auto alloc = [&](size_t bytes) -> void* {
        void* p = ws + off;
        off += (bytes + 255) & ~(size_t)255;
        return p;
    };
    // Zeroed region: cursors + vsum (~4.4 KB).
    unsigned* curD = (unsigned*)alloc((size_t)MAXB * 4);
    unsigned* curS = (unsigned*)alloc((size_t)MAXB * 4);
    float*    vsum = (float*)   alloc(64 * 4);
    size_t zero_bytes = off;
    // No-init region.
    unsigned* bufD  = (unsigned*)alloc((size_t)nbuck * CAP * 4);
    unsigned* bufS  = (unsigned*)alloc((size_t)nbuck * CAP * 4);
    float*    dinv  = (float*)   alloc((size_t)N * 4);
    float*    y     = (float*)   alloc((size_t)N * 8 * 4);
    (void)ws_size; (void)n_in; (void)out_size;

    hipMemsetAsync(d_ws, 0, zero_bytes, stream);

    k_part<<<(E + PCH - 1) / PCH, PTH, 0, stream>>>(src, dst, E, nbuck,
                                                    curD, curS, bufD, bufS);
    k_prep<<<nbuck, 1024, 0, stream>>>(bufD, curD, x, N, dinv, y);
    k_sacc<<<nbuck, 1024, 0, stream>>>(bufD, curD, bufS, curS, y, dinv,
                                       W1, b1, vsum, N);
    k_final<<<1, 64, 0, stream>>>(vsum, W2, b2, state, Wm, bm, Wc, bc,
                                  (float*)d_out, 1.0f / (float)N);
}